// Round 5
// baseline (279.022 us; speedup 1.0000x reference)
//
#include <hip/hip_runtime.h>
#include <math.h>

#define NLk 3
#define NSTATE 65536          // 2^16
#define OUTSTRIDE 131328      // 2*65536 + 256

// One kernel, 64 blocks x 1024 threads.
//  blocks 0..31  : state-vector simulation for batch b (state in 16 named vf4s)
//  blocks 32..63 : Hamiltonian MLP for batch b-32
// Amp index A = (wv<<12) | (var<<8) | (comp<<6) | lane
//   bits 0..5  = lane       -> gates via __shfl_xor
//   bits 6..7  = vf4 comp   -> gates on .x/.y/.z/.w of one variable
//   bits 8..11 = var index  -> gates between named variables v0..v15
//   bits 12..15= wave id    -> gates via LDS vf4 exchange (128KB, 2 chunks)
//
// R1-R4 lesson: float a[64] stayed an un-promoted alloca in scratch across
// every attribute/template variant (VGPR_Count pinned at 64, ~8.4MB dirty
// scratch writeback + L2-latency-bound gates). 16 named ext_vector variables
// cannot be an alloca: the state is SSA by construction.

typedef float vf4 __attribute__((ext_vector_type(4)));

// ---- per-variable ops (capture locals textually) ----
#define SHFLMIX(v) { float ox=__shfl_xor(v.x,msk,64), oy=__shfl_xor(v.y,msk,64), \
                           oz=__shfl_xor(v.z,msk,64), ow=__shfl_xor(v.w,msk,64); \
  v.x=cown*v.x+coth*ox; v.y=cown*v.y+coth*oy; v.z=cown*v.z+coth*oz; v.w=cown*v.w+coth*ow; }

#define ESHFL(v) { float ox=__shfl_xor(v.x,msk,64), oy=__shfl_xor(v.y,msk,64), \
                         oz=__shfl_xor(v.z,msk,64), ow=__shfl_xor(v.w,msk,64); \
  v.x+=pe*(ox-v.x); v.y+=pe*(oy-v.y); v.z+=pe*(oz-v.z); v.w+=pe*(ow-v.w); }

#define C0MIX(v) { float nx=r00*v.x+r01*v.y, ny=r10*v.x+r11*v.y, \
                         nz=r00*v.z+r01*v.w, nw=r10*v.z+r11*v.w; \
  v.x=nx; v.y=ny; v.z=nz; v.w=nw; }

#define C1MIX(v) { float nx=r00*v.x+r01*v.z, nz=r10*v.x+r11*v.z, \
                         ny=r00*v.y+r01*v.w, nw=r10*v.y+r11*v.w; \
  v.x=nx; v.y=ny; v.z=nz; v.w=nw; }

#define PAIRMIX(A,B) { float t; \
  t=A.x; A.x=r00*t+r01*B.x; B.x=r10*t+r11*B.x; \
  t=A.y; A.y=r00*t+r01*B.y; B.y=r10*t+r11*B.y; \
  t=A.z; A.z=r00*t+r01*B.z; B.z=r10*t+r11*B.z; \
  t=A.w; A.w=r00*t+r01*B.w; B.w=r10*t+r11*B.w; }

#define E5MIX(v) { float d=pe*(v.y-v.x); v.x+=d; v.y-=d; \
                   float d2=pe*(v.w-v.z); v.z+=d2; v.w-=d2; }

#define E6MIX(v) { float d=p*(v.w-v.y); v.y+=d; v.w-=d; }

#define E7MIX(A,B) { float d=p*(B.z-A.z); A.z+=d; B.z-=d; \
                     float d2=p*(B.w-A.w); A.w+=d2; B.w-=d2; }

#define EPAIR(A,B) { float d; \
  d=p*(B.x-A.x); A.x+=d; B.x-=d; \
  d=p*(B.y-A.y); A.y+=d; B.y-=d; \
  d=p*(B.z-A.z); A.z+=d; B.z-=d; \
  d=p*(B.w-A.w); A.w+=d; B.w-=d; }

#define WST(v,j) s_x4[(j)*1024+tid]=v;
#define RLD(v,j) { vf4 o=s_x4[(j)*1024+pbase]; \
  v.x=cown*v.x+coth*o.x; v.y=cown*v.y+coth*o.y; v.z=cown*v.z+coth*o.z; v.w=cown*v.w+coth*o.w; }
#define ELD(v,j) { vf4 o=s_x4[(j)*1024+pbase]; \
  v.x+=p*(o.x-v.x); v.y+=p*(o.y-v.y); v.z+=p*(o.z-v.z); v.w+=p*(o.w-v.w); }

#define ALLV(OP) OP(v0) OP(v1) OP(v2) OP(v3) OP(v4) OP(v5) OP(v6) OP(v7) \
                 OP(v8) OP(v9) OP(v10) OP(v11) OP(v12) OP(v13) OP(v14) OP(v15)
#define CH0(OP) OP(v0,0) OP(v1,1) OP(v2,2) OP(v3,3) OP(v4,4) OP(v5,5) OP(v6,6) OP(v7,7)
#define CH1(OP) OP(v8,0) OP(v9,1) OP(v10,2) OP(v11,3) OP(v12,4) OP(v13,5) OP(v14,6) OP(v15,7)

// ---- gates ----
#define ROT_LANE(Q) { \
  const float r00=rc[(Q)*4+0], r01=rc[(Q)*4+1], r10=rc[(Q)*4+2], r11=rc[(Q)*4+3]; \
  const int msk=1<<(Q); const int bit=(lane>>(Q))&1; \
  const float cown=bit?r11:r00, coth=bit?r10:r01; \
  ALLV(SHFLMIX) }

#define ROT_C0 { const float r00=rc[24], r01=rc[25], r10=rc[26], r11=rc[27]; ALLV(C0MIX) }
#define ROT_C1 { const float r00=rc[28], r01=rc[29], r10=rc[30], r11=rc[31]; ALLV(C1MIX) }

#define ROT_V0 { const float r00=rc[32],r01=rc[33],r10=rc[34],r11=rc[35]; \
  PAIRMIX(v0,v1) PAIRMIX(v2,v3) PAIRMIX(v4,v5) PAIRMIX(v6,v7) \
  PAIRMIX(v8,v9) PAIRMIX(v10,v11) PAIRMIX(v12,v13) PAIRMIX(v14,v15) }
#define ROT_V1 { const float r00=rc[36],r01=rc[37],r10=rc[38],r11=rc[39]; \
  PAIRMIX(v0,v2) PAIRMIX(v1,v3) PAIRMIX(v4,v6) PAIRMIX(v5,v7) \
  PAIRMIX(v8,v10) PAIRMIX(v9,v11) PAIRMIX(v12,v14) PAIRMIX(v13,v15) }
#define ROT_V2 { const float r00=rc[40],r01=rc[41],r10=rc[42],r11=rc[43]; \
  PAIRMIX(v0,v4) PAIRMIX(v1,v5) PAIRMIX(v2,v6) PAIRMIX(v3,v7) \
  PAIRMIX(v8,v12) PAIRMIX(v9,v13) PAIRMIX(v10,v14) PAIRMIX(v11,v15) }
#define ROT_V3 { const float r00=rc[44],r01=rc[45],r10=rc[46],r11=rc[47]; \
  PAIRMIX(v0,v8) PAIRMIX(v1,v9) PAIRMIX(v2,v10) PAIRMIX(v3,v11) \
  PAIRMIX(v4,v12) PAIRMIX(v5,v13) PAIRMIX(v6,v14) PAIRMIX(v7,v15) }

#define ROT_WAVE(Q) { \
  const float r00=rc[(Q)*4+0], r01=rc[(Q)*4+1], r10=rc[(Q)*4+2], r11=rc[(Q)*4+3]; \
  const int bit=(wv>>((Q)-12))&1; \
  const float cown=bit?r11:r00, coth=bit?r10:r01; \
  const int pbase=((wv^(1<<((Q)-12)))<<6)|lane; \
  __syncthreads(); CH0(WST) __syncthreads(); CH0(RLD) \
  __syncthreads(); CH1(WST) __syncthreads(); CH1(RLD) }

#define ENT_LANE(C) { const float p=ec[C]; \
  const float pe=((lane>>(C))&1)?p:0.f; const int msk=2<<(C); \
  ALLV(ESHFL) }

#define ENT_WAVE(C) { const float p=ec[C]; \
  const int cbv=(wv>>((C)-12))&1; \
  const int pbase=((wv^(1<<((C)-11)))<<6)|lane; \
  __syncthreads(); if(cbv){ CH0(WST) } __syncthreads(); if(cbv){ CH0(ELD) } \
  __syncthreads(); if(cbv){ CH1(WST) } __syncthreads(); if(cbv){ CH1(ELD) } }

__global__ __attribute__((amdgpu_flat_work_group_size(1024,1024)))
__attribute__((amdgpu_waves_per_eu(4,4))) void vqe_fused(
    const float* __restrict__ coords, const float* __restrict__ feats,
    const float* __restrict__ rotp,   const float* __restrict__ entp,
    const float* __restrict__ fpw1,   const float* __restrict__ fpb1,
    const float* __restrict__ fpw2,   const float* __restrict__ fpb2,
    const float* __restrict__ hcw1,   const float* __restrict__ hcb1,
    const float* __restrict__ hcw2,   const float* __restrict__ hcb2,
    const float* __restrict__ hcw3,   const float* __restrict__ hcb3,
    float* __restrict__ out)
{
  __shared__ vf4 s_x4[8*1024];        // 128KB exchange buffer
  __shared__ float s_pf[16];
  __shared__ float s_rot[NLk*16*4];   // r00,r01,r10,r11 per (layer,qubit)
  __shared__ float s_ent[NLk*15];     // sigmoid(ent)

  float* s_x = (float*)s_x4;          // scalar alias for MLP temps

  const int tid = threadIdx.x;
  const int bid = blockIdx.x;

  if (bid >= 32) {
    // ---------------- Hamiltonian block ----------------
    const int b = bid - 32;
    float* xh = s_x;          // 60
    float* h1 = s_x + 64;     // 256
    float* h2 = s_x + 384;    // 128
    float* h3 = s_x + 512;    // 256
    if (tid < 60) xh[tid] = coords[b*60 + tid];
    __syncthreads();
    if (tid < 256) {
      float acc = hcb1[tid];
      const float* w = hcw1 + tid*60;
      for (int k = 0; k < 60; ++k) acc += w[k]*xh[k];
      h1[tid] = fmaxf(acc, 0.f);
    }
    __syncthreads();
    if (tid < 128) {
      float acc = hcb2[tid];
      const float* w = hcw2 + tid*256;
      for (int k = 0; k < 256; ++k) acc += w[k]*h1[k];
      h2[tid] = fmaxf(acc, 0.f);
    }
    __syncthreads();
    if (tid < 256) {
      float acc = hcb3[tid];
      const float* w = hcw3 + tid*128;
      for (int k = 0; k < 128; ++k) acc += w[k]*h2[k];
      h3[tid] = acc;
    }
    __syncthreads();
    if (tid < 256) {
      float s = 0.f, sq = 0.f;
      for (int k = 0; k < 60; ++k) { float v = xh[k]; s += v; sq += v*v; }
      float mean = s * (1.f/60.f);
      float var  = (sq - 60.f*mean*mean) * (1.f/59.f);
      float freq = sqrtf(1.f/(var + 1e-6f)) * 200.f;
      int i = tid >> 4, j = tid & 15;
      float v = 0.5f*(h3[tid] + h3[j*16 + i]) + ((i==j) ? freq : 0.f);
      out[(size_t)b*OUTSTRIDE + 2*NSTATE + tid] = v;
    }
    return;
  }

  // ---------------- Simulation block ----------------
  const int b    = bid;
  const int lane = tid & 63;
  const int wv   = tid >> 6;

  // Phase 0a: feature-MLP hidden layer (64) + entangler sigmoids (45)
  if (tid < 64) {
    float acc = fpb1[tid];
    const float* w = fpw1 + tid*100;
    const float* f = feats + b*100;
    for (int k = 0; k < 100; ++k) acc += w[k]*f[k];
    s_x[tid] = fmaxf(acc, 0.f);
  } else if (tid < 64+45) {
    int c = tid - 64;
    s_ent[c] = 1.f / (1.f + expf(-entp[c]));
  }
  __syncthreads();
  // Phase 0b: pf = tanh(h1 @ w2^T + b2)
  if (tid < 16) {
    float acc = fpb2[tid];
    const float* w = fpw2 + tid*64;
    for (int k = 0; k < 64; ++k) acc += w[k]*s_x[k];
    s_pf[tid] = tanhf(acc);
  }
  __syncthreads();
  // Phase 0c: rotation matrices (row0=[cxcycz,-sxsysz], row1=[sxsycz,cxcysz])
  if (tid < 48) {                       // tid = layer*16 + q
    float ang = s_pf[tid & 15];
    const float* rp = rotp + tid*3;
    float cx = cosf(0.5f*rp[0]*ang), sx = sinf(0.5f*rp[0]*ang);
    float cy = cosf(0.5f*rp[1]*ang), sy = sinf(0.5f*rp[1]*ang);
    float cz = cosf(0.5f*rp[2]*ang), sz = sinf(0.5f*rp[2]*ang);
    s_rot[tid*4+0] =  cx*cy*cz;
    s_rot[tid*4+1] = -sx*sy*sz;
    s_rot[tid*4+2] =  sx*sy*cz;
    s_rot[tid*4+3] =  cx*cy*sz;
  }
  __syncthreads();

  // State: 16 named vf4s = 64 amps/thread. SSA by construction (no alloca).
  vf4 v0=(vf4)0.f, v1=(vf4)0.f, v2=(vf4)0.f, v3=(vf4)0.f,
      v4=(vf4)0.f, v5=(vf4)0.f, v6=(vf4)0.f, v7=(vf4)0.f,
      v8=(vf4)0.f, v9=(vf4)0.f, v10=(vf4)0.f, v11=(vf4)0.f,
      v12=(vf4)0.f, v13=(vf4)0.f, v14=(vf4)0.f, v15=(vf4)0.f;
  if (tid == 0) v0.x = 1.f;

  #pragma unroll 1
  for (int lay = 0; lay < NLk; ++lay) {
    const float* rc = s_rot + lay*64;
    const float* ec = s_ent + lay*15;
    // rotations q = 0..15
    ROT_LANE(0) ROT_LANE(1) ROT_LANE(2) ROT_LANE(3) ROT_LANE(4) ROT_LANE(5)
    ROT_C0 ROT_C1
    ROT_V0 ROT_V1 ROT_V2 ROT_V3
    ROT_WAVE(12) ROT_WAVE(13) ROT_WAVE(14) ROT_WAVE(15)
    // entanglers c = 0..14 (ctrl=bit c, target=bit c+1)
    ENT_LANE(0) ENT_LANE(1) ENT_LANE(2) ENT_LANE(3) ENT_LANE(4)
    { const float pe = ((lane>>5)&1) ? ec[5] : 0.f; ALLV(E5MIX) }       // c=5
    { const float p = ec[6]; ALLV(E6MIX) }                               // c=6
    { const float p = ec[7];                                             // c=7
      E7MIX(v0,v1) E7MIX(v2,v3) E7MIX(v4,v5) E7MIX(v6,v7)
      E7MIX(v8,v9) E7MIX(v10,v11) E7MIX(v12,v13) E7MIX(v14,v15) }
    { const float p = ec[8];  EPAIR(v1,v3) EPAIR(v5,v7) EPAIR(v9,v11) EPAIR(v13,v15) }
    { const float p = ec[9];  EPAIR(v2,v6) EPAIR(v3,v7) EPAIR(v10,v14) EPAIR(v11,v15) }
    { const float p = ec[10]; EPAIR(v4,v12) EPAIR(v5,v13) EPAIR(v6,v14) EPAIR(v7,v15) }
    { const float p = ec[11]; const int pbase = ((wv^1)<<6)|lane;        // c=11
      __syncthreads(); CH1(WST) __syncthreads(); CH1(ELD) }
    ENT_WAVE(12) ENT_WAVE(13) ENT_WAVE(14)
  }

  // ---- epilogue: real amps + zero imag (state is provably real) ----
  {
    float* orr = out + (size_t)b*OUTSTRIDE;
    const int base = (wv<<12)|lane;
    #define STV(v,r) orr[base+((r)<<8)+  0]=v.x; orr[base+((r)<<8)+ 64]=v.y; \
                     orr[base+((r)<<8)+128]=v.z; orr[base+((r)<<8)+192]=v.w;
    STV(v0,0)  STV(v1,1)  STV(v2,2)  STV(v3,3)
    STV(v4,4)  STV(v5,5)  STV(v6,6)  STV(v7,7)
    STV(v8,8)  STV(v9,9)  STV(v10,10) STV(v11,11)
    STV(v12,12) STV(v13,13) STV(v14,14) STV(v15,15)
    vf4* oz = (vf4*)(orr + NSTATE);
    const vf4 z4 = (vf4)0.f;
    #pragma unroll
    for (int k = 0; k < 16; ++k)
      oz[k*1024 + tid] = z4;
  }
}

extern "C" void kernel_launch(void* const* d_in, const int* in_sizes, int n_in,
                              void* d_out, int out_size, void* d_ws, size_t ws_size,
                              hipStream_t stream) {
  vqe_fused<<<dim3(64), dim3(1024), 0, stream>>>(
      (const float*)d_in[0],  (const float*)d_in[1],
      (const float*)d_in[2],  (const float*)d_in[3],
      (const float*)d_in[4],  (const float*)d_in[5],
      (const float*)d_in[6],  (const float*)d_in[7],
      (const float*)d_in[8],  (const float*)d_in[9],
      (const float*)d_in[10], (const float*)d_in[11],
      (const float*)d_in[12], (const float*)d_in[13],
      (float*)d_out);
}

// Round 6
// 161.607 us; speedup vs baseline: 1.7265x; 1.7265x over previous
//
#include <hip/hip_runtime.h>
#include <math.h>

#define NSTATE 65536          // 2^16
#define OUTSTRIDE 131328      // 2*65536 + 256
#define CW 256                // ws floats per batch: [0..191] rot coefs, [192..236] ent sigmoids

// ============================================================================
// R5 lesson: the single-block-per-batch design is LDS-PIPE bound (shfl_xor =
// ds_swizzle, wave exchange = ds_rw_b128; ~330K LDS cycles/CU = ~140us on just
// 32 CUs; VALUBusy 3%). VGPR=64 was never a spill. Fix: spread each batch over
// 8 blocks (256 CUs). Qubits 0-2 become BLOCK bits; the only gates touching
// them (rot0-2, ent0, ent1) are applied as composite 8x8 matrices at kernel-
// launch boundaries via a coalesced 8-float gather. Commutation (rot0,rot1 of
// layer l+1 commute past ent2-14 of layer l; rot2 joins the next boundary)
// compresses the circuit to 4 gate launches:
//   G1: [R0R1R2 l0 from |0>]            + local rot3-15(l0)
//   G2: [E0E1(l0) . R0R1(l1)]  gather   + local ent2-14(l0), rot3-15(l1)
//   G3: [R2(l1) E0E1(l1) R0R1(l2)]      + local ent2-14(l1), rot3-15(l2)
//   G4: [R2(l2) E0E1(l2)]               + local ent2-14(l2)  -> final real
// State ping-pongs between d_out's imag and real regions; imag zeroed last.
// Amp index A: bit k = qubit k. Block(batch b = bid&31, om = bid>>5) owns
// A[2:0]==om (bid&31 keeps a batch's 8 blocks on one XCD for L2 gather reuse).
// Thread (wv=tid>>6, lane=tid&63) slot j(0-7): A = j<<13 | wv<<9 | lane<<3 | om
//   qubits 3-8  = lane bits  -> shfl_xor      (8 swizzles/gate, was 64)
//   qubits 9-12 = wave bits  -> LDS exchange  (2 b128 w + 2 r /gate)
//   qubits 13-15= j bits     -> pure VALU on v0/v1 components
// ============================================================================

__global__ __launch_bounds__(256) void k_coef(
    const float* __restrict__ coords, const float* __restrict__ feats,
    const float* __restrict__ rotp,   const float* __restrict__ entp,
    const float* __restrict__ fpw1,   const float* __restrict__ fpb1,
    const float* __restrict__ fpw2,   const float* __restrict__ fpb2,
    const float* __restrict__ hcw1,   const float* __restrict__ hcb1,
    const float* __restrict__ hcw2,   const float* __restrict__ hcb2,
    const float* __restrict__ hcw3,   const float* __restrict__ hcb3,
    float* __restrict__ out, float* __restrict__ coef)
{
  __shared__ float xh[60], fh[64], pf[16], h1[256], h2[128], h3[256];
  const int tid = threadIdx.x;
  const int b = blockIdx.x;
  if (tid < 60) xh[tid] = coords[b*60 + tid];
  if (tid < 64) {
    float acc = fpb1[tid];
    const float* w = fpw1 + tid*100;
    const float* f = feats + b*100;
    for (int k = 0; k < 100; ++k) acc += w[k]*f[k];
    fh[tid] = fmaxf(acc, 0.f);
  } else if (tid < 64+45) {
    coef[b*CW + 192 + (tid-64)] = 1.f/(1.f + expf(-entp[tid-64]));
  }
  __syncthreads();
  if (tid < 16) {
    float acc = fpb2[tid];
    const float* w = fpw2 + tid*64;
    for (int k = 0; k < 64; ++k) acc += w[k]*fh[k];
    pf[tid] = tanhf(acc);
  }
  {
    float acc = hcb1[tid];
    const float* w = hcw1 + tid*60;
    for (int k = 0; k < 60; ++k) acc += w[k]*xh[k];
    h1[tid] = fmaxf(acc, 0.f);
  }
  __syncthreads();
  if (tid < 48) {                       // tid = layer*16 + q
    float ang = pf[tid & 15];
    const float* rp = rotp + tid*3;
    float cx = cosf(0.5f*rp[0]*ang), sx = sinf(0.5f*rp[0]*ang);
    float cy = cosf(0.5f*rp[1]*ang), sy = sinf(0.5f*rp[1]*ang);
    float cz = cosf(0.5f*rp[2]*ang), sz = sinf(0.5f*rp[2]*ang);
    float* cc = coef + b*CW + tid*4;
    cc[0] =  cx*cy*cz; cc[1] = -sx*sy*sz; cc[2] = sx*sy*cz; cc[3] = cx*cy*sz;
  }
  if (tid < 128) {
    float acc = hcb2[tid];
    const float* w = hcw2 + tid*256;
    for (int k = 0; k < 256; ++k) acc += w[k]*h1[k];
    h2[tid] = fmaxf(acc, 0.f);
  }
  __syncthreads();
  {
    float acc = hcb3[tid];
    const float* w = hcw3 + tid*128;
    for (int k = 0; k < 128; ++k) acc += w[k]*h2[k];
    h3[tid] = acc;
  }
  __syncthreads();
  {
    float s = 0.f, sq = 0.f;
    for (int k = 0; k < 60; ++k) { float v = xh[k]; s += v; sq += v*v; }
    float mean = s*(1.f/60.f);
    float var  = (sq - 60.f*mean*mean)*(1.f/59.f);
    float freq = sqrtf(1.f/(var + 1e-6f))*200.f;
    int i = tid >> 4, j = tid & 15;
    out[(size_t)b*OUTSTRIDE + 2*NSTATE + tid] =
        0.5f*(h3[tid] + h3[j*16 + i]) + ((i==j) ? freq : 0.f);
  }
}

// ---- boundary-row builders (row `om` of composite 8x8; reverse-chron apply) ----
#define RP(A,B) { float t=A; A = t*g00 + B*g10; B = B*g11 + t*g01; }
#define RB0 RP(r0,r1) RP(r2,r3) RP(r4,r5) RP(r6,r7)
#define RB1 RP(r0,r2) RP(r1,r3) RP(r4,r6) RP(r5,r7)
#define RB2 RP(r0,r4) RP(r1,r5) RP(r2,r6) RP(r3,r7)
#define RRB(l,q,BITS) { const float* gg = sc + ((l)*16+(q))*4; \
  const float g00=gg[0], g01=gg[1], g10=gg[2], g11=gg[3]; BITS }
#define EP(A,B) { float t=A; A = (1.f-p)*A + p*B; B = (1.f-p)*B + p*t; }
#define REB0(l) { const float p = sc[192+(l)*15+0]; EP(r1,r3) EP(r5,r7) }   // ent0: ctrl b0, tgt b1
#define REB1(l) { const float p = sc[192+(l)*15+1]; EP(r2,r6) EP(r3,r7) }   // ent1: ctrl b1, tgt b2

// ---- local gates ----
#define SH4(v) { float ox=__shfl_xor(v.x,msk,64), oy=__shfl_xor(v.y,msk,64), \
                       oz=__shfl_xor(v.z,msk,64), ow=__shfl_xor(v.w,msk,64); \
  v.x=cown*v.x+coth*ox; v.y=cown*v.y+coth*oy; v.z=cown*v.z+coth*oz; v.w=cown*v.w+coth*ow; }
#define ROTL(l,q) { const float* gg = sc + ((l)*16+(q))*4; \
  const float g00=gg[0], g01=gg[1], g10=gg[2], g11=gg[3]; \
  const int msk = 1<<((q)-3); const int lb = (lane>>((q)-3))&1; \
  const float cown = lb?g11:g00, coth = lb?g10:g01; SH4(v0) SH4(v1) }
#define ROTW(l,q) { const float* gg = sc + ((l)*16+(q))*4; \
  const float g00=gg[0], g01=gg[1], g10=gg[2], g11=gg[3]; \
  const int k=(q)-9; const int bt=(wv>>k)&1; \
  const float cown = bt?g11:g00, coth = bt?g10:g01; \
  const int pb = ((wv^(1<<k))<<6)|lane; \
  __syncthreads(); xbuf[tid]=v0; xbuf[1024+tid]=v1; __syncthreads(); \
  { float4 o=xbuf[pb];      v0.x=cown*v0.x+coth*o.x; v0.y=cown*v0.y+coth*o.y; \
                            v0.z=cown*v0.z+coth*o.z; v0.w=cown*v0.w+coth*o.w; } \
  { float4 o=xbuf[1024+pb]; v1.x=cown*v1.x+coth*o.x; v1.y=cown*v1.y+coth*o.y; \
                            v1.z=cown*v1.z+coth*o.z; v1.w=cown*v1.w+coth*o.w; } }
#define ROT13(l) { const float* gg = sc + ((l)*16+13)*4; \
  const float g00=gg[0], g01=gg[1], g10=gg[2], g11=gg[3]; float nx,ny,nz,nw; \
  nx=g00*v0.x+g01*v0.y; ny=g10*v0.x+g11*v0.y; nz=g00*v0.z+g01*v0.w; nw=g10*v0.z+g11*v0.w; \
  v0.x=nx; v0.y=ny; v0.z=nz; v0.w=nw; \
  nx=g00*v1.x+g01*v1.y; ny=g10*v1.x+g11*v1.y; nz=g00*v1.z+g01*v1.w; nw=g10*v1.z+g11*v1.w; \
  v1.x=nx; v1.y=ny; v1.z=nz; v1.w=nw; }
#define ROT14(l) { const float* gg = sc + ((l)*16+14)*4; \
  const float g00=gg[0], g01=gg[1], g10=gg[2], g11=gg[3]; float nx,ny,nz,nw; \
  nx=g00*v0.x+g01*v0.z; nz=g10*v0.x+g11*v0.z; ny=g00*v0.y+g01*v0.w; nw=g10*v0.y+g11*v0.w; \
  v0.x=nx; v0.y=ny; v0.z=nz; v0.w=nw; \
  nx=g00*v1.x+g01*v1.z; nz=g10*v1.x+g11*v1.z; ny=g00*v1.y+g01*v1.w; nw=g10*v1.y+g11*v1.w; \
  v1.x=nx; v1.y=ny; v1.z=nz; v1.w=nw; }
#define ROT15(l) { const float* gg = sc + ((l)*16+15)*4; \
  const float g00=gg[0], g01=gg[1], g10=gg[2], g11=gg[3]; float t; \
  t=v0.x; v0.x=g00*t+g01*v1.x; v1.x=g10*t+g11*v1.x; \
  t=v0.y; v0.y=g00*t+g01*v1.y; v1.y=g10*t+g11*v1.y; \
  t=v0.z; v0.z=g00*t+g01*v1.z; v1.z=g10*t+g11*v1.z; \
  t=v0.w; v0.w=g00*t+g01*v1.w; v1.w=g10*t+g11*v1.w; }

#define ESH(v) { float ox=__shfl_xor(v.x,msk,64), oy=__shfl_xor(v.y,msk,64), \
                       oz=__shfl_xor(v.z,msk,64), ow=__shfl_xor(v.w,msk,64); \
  v.x+=pe*(ox-v.x); v.y+=pe*(oy-v.y); v.z+=pe*(oz-v.z); v.w+=pe*(ow-v.w); }
#define ENT2(l) { const float p = sc[192+(l)*15+2]; const float pe = (om&4)?p:0.f; \
  const int msk = 1; ESH(v0) ESH(v1) }
#define ENTL(l,c) { const float p = sc[192+(l)*15+(c)]; \
  const float pe = ((lane>>((c)-3))&1)?p:0.f; const int msk = 1<<((c)-2); ESH(v0) ESH(v1) }
#define ENT8(l) { const float p = sc[192+(l)*15+8]; \
  const float pe = ((lane>>5)&1)?p:0.f; const int pb = ((wv^1)<<6)|lane; \
  __syncthreads(); xbuf[tid]=v0; xbuf[1024+tid]=v1; __syncthreads(); \
  { float4 o=xbuf[pb];      v0.x+=pe*(o.x-v0.x); v0.y+=pe*(o.y-v0.y); \
                            v0.z+=pe*(o.z-v0.z); v0.w+=pe*(o.w-v0.w); } \
  { float4 o=xbuf[1024+pb]; v1.x+=pe*(o.x-v1.x); v1.y+=pe*(o.y-v1.y); \
                            v1.z+=pe*(o.z-v1.z); v1.w+=pe*(o.w-v1.w); } }
#define ENTW(l,c) { const float p = sc[192+(l)*15+(c)]; const int k=(c)-9; \
  const int cbv = (wv>>k)&1; const int pb = ((wv^(1<<(k+1)))<<6)|lane; \
  __syncthreads(); if(cbv){ xbuf[tid]=v0; xbuf[1024+tid]=v1; } __syncthreads(); \
  if(cbv){ float4 o=xbuf[pb];       v0.x+=p*(o.x-v0.x); v0.y+=p*(o.y-v0.y); \
                                    v0.z+=p*(o.z-v0.z); v0.w+=p*(o.w-v0.w); \
           float4 o1=xbuf[1024+pb]; v1.x+=p*(o1.x-v1.x); v1.y+=p*(o1.y-v1.y); \
                                    v1.z+=p*(o1.z-v1.z); v1.w+=p*(o1.w-v1.w); } }
#define ENT12(l) { const float p = sc[192+(l)*15+12]; const float pe = ((wv>>3)&1)?p:0.f; float d; \
  d=pe*(v0.y-v0.x); v0.x+=d; v0.y-=d;  d=pe*(v0.w-v0.z); v0.z+=d; v0.w-=d; \
  d=pe*(v1.y-v1.x); v1.x+=d; v1.y-=d;  d=pe*(v1.w-v1.z); v1.z+=d; v1.w-=d; }
#define ENT13(l) { const float p = sc[192+(l)*15+13]; float d; \
  d=p*(v0.w-v0.y); v0.y+=d; v0.w-=d;   d=p*(v1.w-v1.y); v1.y+=d; v1.w-=d; }
#define ENT14(l) { const float p = sc[192+(l)*15+14]; float d; \
  d=p*(v1.z-v0.z); v0.z+=d; v1.z-=d;   d=p*(v1.w-v0.w); v0.w+=d; v1.w-=d; }

#define ROTLOC(l) ROTL(l,3) ROTL(l,4) ROTL(l,5) ROTL(l,6) ROTL(l,7) ROTL(l,8) \
  ROTW(l,9) ROTW(l,10) ROTW(l,11) ROTW(l,12) ROT13(l) ROT14(l) ROT15(l)
#define ENTLOC(l) ENT2(l) ENTL(l,3) ENTL(l,4) ENTL(l,5) ENTL(l,6) ENTL(l,7) ENT8(l) \
  ENTW(l,9) ENTW(l,10) ENTW(l,11) ENT12(l) ENT13(l) ENT14(l)

template<int PHASE>
__global__ __launch_bounds__(1024) void k_gate(
    const float* __restrict__ coef, const float* __restrict__ srcbase,
    float* __restrict__ dstbase)
{
  __shared__ float4 xbuf[2048];       // 32KB wave-exchange buffer
  __shared__ float sc[240];
  const int tid = threadIdx.x;
  const int bid = blockIdx.x;
  const int b = bid & 31, om = bid >> 5;
  const int lane = tid & 63, wv = tid >> 6;
  for (int i = tid; i < 240; i += 1024) sc[i] = coef[b*CW + i];
  __syncthreads();

  // row `om` of the boundary composite (built reverse-chronologically)
  float r0=(om==0)?1.f:0.f, r1=(om==1)?1.f:0.f, r2=(om==2)?1.f:0.f, r3=(om==3)?1.f:0.f,
        r4=(om==4)?1.f:0.f, r5=(om==5)?1.f:0.f, r6=(om==6)?1.f:0.f, r7=(om==7)?1.f:0.f;
  if constexpr (PHASE==1) { RRB(0,2,RB2) RRB(0,1,RB1) RRB(0,0,RB0) }
  if constexpr (PHASE==2) { RRB(1,1,RB1) RRB(1,0,RB0) REB1(0) REB0(0) }
  if constexpr (PHASE==3) { RRB(2,1,RB1) RRB(2,0,RB0) REB1(1) REB0(1) RRB(1,2,RB2) }
  if constexpr (PHASE==4) { REB1(2) REB0(2) RRB(2,2,RB2) }

  // load / init state (8 amps: j=0..7 -> v0.xyzw, v1.xyzw)
  float4 v0, v1;
  if constexpr (PHASE==1) {
    v0 = make_float4(0.f,0.f,0.f,0.f); v1 = v0;
    if (tid == 0) v0.x = r0;          // amp A=om of |0> after R0R1R2
  } else {
    const float* srcb = srcbase + (size_t)b*OUTSTRIDE;
    const int gb = (wv<<9) | (lane<<3);
    #define GATH(J, ASSIGN) { const float4* gp = (const float4*)(srcb + ((J)<<13) + gb); \
      float4 lo = gp[0], hi = gp[1]; \
      float amp = r0*lo.x + r1*lo.y + r2*lo.z + r3*lo.w \
                + r4*hi.x + r5*hi.y + r6*hi.z + r7*hi.w; ASSIGN; }
    GATH(0, v0.x=amp) GATH(1, v0.y=amp) GATH(2, v0.z=amp) GATH(3, v0.w=amp)
    GATH(4, v1.x=amp) GATH(5, v1.y=amp) GATH(6, v1.z=amp) GATH(7, v1.w=amp)
    #undef GATH
  }

  // local gates
  if constexpr (PHASE==1) { ROTLOC(0) }
  if constexpr (PHASE==2) { ENTLOC(0) ROTLOC(1) }
  if constexpr (PHASE==3) { ENTLOC(1) ROTLOC(2) }
  if constexpr (PHASE==4) { ENTLOC(2) }

  // store (canonical layout, stride-8 scatter; L2 merges across the 8 octant blocks)
  float* dstb = dstbase + (size_t)b*OUTSTRIDE;
  const int sb = (wv<<9) | (lane<<3) | om;
  dstb[sb + (0<<13)] = v0.x;  dstb[sb + (1<<13)] = v0.y;
  dstb[sb + (2<<13)] = v0.z;  dstb[sb + (3<<13)] = v0.w;
  dstb[sb + (4<<13)] = v1.x;  dstb[sb + (5<<13)] = v1.y;
  dstb[sb + (6<<13)] = v1.z;  dstb[sb + (7<<13)] = v1.w;
}

__global__ __launch_bounds__(1024) void k_zero(float* __restrict__ out) {
  const int tid = threadIdx.x, bid = blockIdx.x;
  const int b = bid & 31, part = bid >> 5;
  float4* p = (float4*)(out + (size_t)b*OUTSTRIDE + NSTATE);
  const float4 z = make_float4(0.f,0.f,0.f,0.f);
  p[part*2048 + tid] = z;
  p[part*2048 + 1024 + tid] = z;
}

extern "C" void kernel_launch(void* const* d_in, const int* in_sizes, int n_in,
                              void* d_out, int out_size, void* d_ws, size_t ws_size,
                              hipStream_t stream) {
  float* out  = (float*)d_out;
  float* coef = (float*)d_ws;          // 32*256 floats = 32KB
  k_coef<<<32, 256, 0, stream>>>(
      (const float*)d_in[0],  (const float*)d_in[1],
      (const float*)d_in[2],  (const float*)d_in[3],
      (const float*)d_in[4],  (const float*)d_in[5],
      (const float*)d_in[6],  (const float*)d_in[7],
      (const float*)d_in[8],  (const float*)d_in[9],
      (const float*)d_in[10], (const float*)d_in[11],
      (const float*)d_in[12], (const float*)d_in[13],
      out, coef);
  // state ping-pong: G1 -> imag region, G2 -> real, G3 -> imag, G4 -> real (final)
  k_gate<1><<<256, 1024, 0, stream>>>(coef, out + NSTATE, out + NSTATE);
  k_gate<2><<<256, 1024, 0, stream>>>(coef, out + NSTATE, out);
  k_gate<3><<<256, 1024, 0, stream>>>(coef, out,          out + NSTATE);
  k_gate<4><<<256, 1024, 0, stream>>>(coef, out + NSTATE, out);
  k_zero<<<256, 1024, 0, stream>>>(out);   // imag = 0 (after G4's reads)
}